// Round 11
// baseline (120.588 us; speedup 1.0000x reference)
//
#include <hip/hip_runtime.h>

// Problem constants
#define NBOOKS 4
#define CODES  1024
#define DIM    64
#define NPOS   32768          // B*T*H*W
#define CCH    256            // NB*DIM (channel dim of z)
#define ENC_OFF  8388608
#define LOSS_OFF 8519680
#define PERP_OFF 8519681

// workspace byte offsets
#define WS_E2      0              // 4096 f32 (raw ||e||^2)
#define WS_EHI     16384          // 4096*64 f16 = 512 KB  (hi of -2*e)
#define WS_ELO     540672         // 512 KB                 (lo of -2*e)
#define WS_IDX     1064960        // 131072 int
#define WS_CNT     1589248        // 4096 int
#define WS_PART    1605632        // 128 f32
#define WS_FLAGCNT 1607680        // 1 int
#define WS_FLAGS   1607696        // 131072 int

typedef _Float16 f16x8 __attribute__((ext_vector_type(8)));
typedef _Float16 f16x4 __attribute__((ext_vector_type(4)));
typedef float    f32x4 __attribute__((ext_vector_type(4)));

// ------------------------------------------- prep: e2, hi/lo f16(-2e), zeroing
__global__ void k_eprep2(const float* __restrict__ emb, float* __restrict__ e2,
                         _Float16* __restrict__ ehi, _Float16* __restrict__ elo,
                         int* __restrict__ counts, int* __restrict__ flagcnt) {
    int i = blockIdx.x * 256 + threadIdx.x;            // row 0..4095 = k*1024+c
    counts[i] = 0;
    if (i == 0) *flagcnt = 0;
    const float4* e = (const float4*)(emb + ((size_t)i << 6));
    _Float16* hp = ehi + ((size_t)i << 6);
    _Float16* lp = elo + ((size_t)i << 6);
    float s = 0.f;
#pragma unroll
    for (int j = 0; j < 16; ++j) {
        float4 v = e[j];
        s += v.x * v.x + v.y * v.y + v.z * v.z + v.w * v.w;
        f16x4 hv, lv;
        float m;
        m = -2.f * v.x; hv[0] = (_Float16)m; lv[0] = (_Float16)(m - (float)hv[0]);
        m = -2.f * v.y; hv[1] = (_Float16)m; lv[1] = (_Float16)(m - (float)hv[1]);
        m = -2.f * v.z; hv[2] = (_Float16)m; lv[2] = (_Float16)(m - (float)hv[2]);
        m = -2.f * v.w; hv[3] = (_Float16)m; lv[3] = (_Float16)(m - (float)hv[3]);
        *(f16x4*)&hp[j * 4] = hv;
        *(f16x4*)&lp[j * 4] = lv;
    }
    e2[i] = s;           // raw ||e||^2; score = e2 - 2x.e (may be negative: ok)
}

// ---------------------------------------------------------------- MFMA argmin v7
// Block = 128 positions x all 1024 codes, one book; 4 waves x 32 pos each,
// 4 blocks/CU. X direct global->regs. acc init = e2v (raw) -> score =
// ||e||^2 - 2x.e (monotone in distance; may be NEGATIVE -> tracking is done
// in the FLOAT domain where ordering is correct; equal-truncation ties are
// always flagged and fixed by exact rescore).
// 3-op tracking per candidate: key = as_float((bits&~63)|kit);
//   m2 = fmed3(m1, m2, key)   [exact second-min update]
//   m1 = fmin(m1, key)
// E streamed in 32-code chunks (8 KB hi+lo), 3-buffer, 1 barrier/chunk,
// XOR-swizzled write+read; e2 values prefetched one chunk ahead.
__global__ void __launch_bounds__(256, 4) k_argmin_mfma(
        const float* __restrict__ z, const float* __restrict__ e2g,
        const _Float16* __restrict__ ehi, const _Float16* __restrict__ elo,
        int* __restrict__ idxbuf, int* __restrict__ flagcnt,
        int* __restrict__ flaglist) {
    __shared__ __attribute__((aligned(16))) char sE[3][8192];  // hi[0,4K) lo[4K,8K)

    int tid = threadIdx.x;
    int wave = tid >> 6, lane = tid & 63;
    int lrow = lane >> 4, lcol = lane & 15;
    int k = blockIdx.y;
    int posbase = blockIdx.x * 128;
    int b = posbase >> 13, s0 = posbase & 8191;
    int wb = wave * 32;

    // ---- X fragments straight into registers
    const float* zb = z + (((size_t)(b * CCH + k * DIM)) << 13) + s0 + wb;
    f16x8 Xh[2][2], Xl[2][2];
#pragma unroll
    for (int pt = 0; pt < 2; ++pt)
#pragma unroll
        for (int kc = 0; kc < 2; ++kc) {
            f16x8 hv, lv;
#pragma unroll
            for (int e = 0; e < 8; ++e) {
                int d = kc * 32 + lrow * 8 + e;
                float f = zb[((size_t)d << 13) + pt * 16 + lcol];
                _Float16 h = (_Float16)f;
                hv[e] = h;
                lv[e] = (_Float16)(f - (float)h);
            }
            Xh[pt][kc] = hv; Xl[pt][kc] = lv;
        }

    // ---- E staging params: thread moves 32 B (two swizzled 16B pieces)/chunk
    int half = tid >> 7;                  // 0: hi, 1: lo
    int u = tid & 127;
    int r = u >> 2, q = u & 3;            // code row 0..31, 32B quarter 0..3
    const char* bookh = (const char*)((half ? elo : ehi) + ((size_t)k << 16));
    const char* src0 = bookh + r * 128 + q * 32;          // + chunk*4096
    int c0 = 2 * q, c1 = 2 * q + 1;
    int w0 = half * 4096 + r * 128 + ((c0 ^ (r & 7)) << 4);
    int w1 = half * 4096 + r * 128 + ((c1 ^ (r & 7)) << 4);

    const float* e2p = e2g + (k << 10) + lrow * 4;

    // prologue: stage chunk 0 into buffer 0; load chunk-0 e2 vectors
    {
        f16x8 v0 = *(const f16x8*)(src0);
        f16x8 v1 = *(const f16x8*)(src0 + 16);
        *(f16x8*)&sE[0][w0] = v0;
        *(f16x8*)&sE[0][w1] = v1;
    }
    f32x4 ce2a = *(const f32x4*)(e2p);
    f32x4 ce2b = *(const f32x4*)(e2p + 16);

    float m1f[2][4], m2f[2][4];
#pragma unroll
    for (int pt = 0; pt < 2; ++pt)
#pragma unroll
        for (int rr = 0; rr < 4; ++rr) { m1f[pt][rr] = 3.4e38f; m2f[pt][rr] = 3.4e38f; }

    int sx = (lcol & 7) << 4;
    int o0 = (lrow << 4) ^ sx;            // K-chunk 0 (dims 0..31)
    int o1 = ((4 + lrow) << 4) ^ sx;      // K-chunk 1 (dims 32..63)
    int rbase = lcol << 7;                // code row stride 128 B (+ st*2048)

    int cur = 0, nxt = 1, fre = 2;
    for (int it = 0; it < 32; ++it) {
        f16x8 nv0, nv1;
        f32x4 ne2a, ne2b;
        bool has = it < 31;
        if (has) {
            const char* sp = src0 + (size_t)(it + 1) * 4096;
            nv0 = *(const f16x8*)(sp);
            nv1 = *(const f16x8*)(sp + 16);
            ne2a = *(const f32x4*)(e2p + (it + 1) * 32);
            ne2b = *(const f32x4*)(e2p + (it + 1) * 32 + 16);
        }
        __syncthreads();
        const char* sc = sE[cur];
#pragma unroll
        for (int st = 0; st < 2; ++st) {
            const char* rb = sc + st * 2048 + rbase;
            f16x8 eh0 = *(const f16x8*)(rb + o0);
            f16x8 eh1 = *(const f16x8*)(rb + o1);
            f16x8 el0 = *(const f16x8*)(rb + 4096 + o0);
            f16x8 el1 = *(const f16x8*)(rb + 4096 + o1);
            f32x4 e2v = st ? ce2b : ce2a;
            unsigned kit = (unsigned)(it * 2 + st);
#pragma unroll
            for (int pt = 0; pt < 2; ++pt) {
                f32x4 acc = e2v;          // score = ||e||^2 - 2x.e (sign ok)
                acc = __builtin_amdgcn_mfma_f32_16x16x32_f16(eh0, Xh[pt][0], acc, 0, 0, 0);
                acc = __builtin_amdgcn_mfma_f32_16x16x32_f16(eh0, Xl[pt][0], acc, 0, 0, 0);
                acc = __builtin_amdgcn_mfma_f32_16x16x32_f16(el0, Xh[pt][0], acc, 0, 0, 0);
                acc = __builtin_amdgcn_mfma_f32_16x16x32_f16(eh1, Xh[pt][1], acc, 0, 0, 0);
                acc = __builtin_amdgcn_mfma_f32_16x16x32_f16(eh1, Xl[pt][1], acc, 0, 0, 0);
                acc = __builtin_amdgcn_mfma_f32_16x16x32_f16(el1, Xh[pt][1], acc, 0, 0, 0);
#pragma unroll
                for (int rr = 0; rr < 4; ++rr) {
                    float key = __uint_as_float(
                        (__float_as_uint(acc[rr]) & 0xFFFFFFC0u) | kit);
                    m2f[pt][rr] = __builtin_amdgcn_fmed3f(m1f[pt][rr], m2f[pt][rr], key);
                    m1f[pt][rr] = fminf(m1f[pt][rr], key);
                }
            }
        }
        if (has) {
            *(f16x8*)&sE[nxt][w0] = nv0;
            *(f16x8*)&sE[nxt][w1] = nv1;
            ce2a = ne2a; ce2b = ne2b;
        }
        int t = cur; cur = nxt; nxt = fre; fre = t;
    }

    // ---- within-thread merge over r slots (exact, index tie-break)
    float F1[2], F2[2]; int I1[2];
#pragma unroll
    for (int pt = 0; pt < 2; ++pt) {
        float f1 = 3.4e38f, f2 = 3.4e38f; int i1 = 0;
#pragma unroll
        for (int rr = 0; rr < 4; ++rr) {
            unsigned mb = __float_as_uint(m1f[pt][rr]);
            float f = __uint_as_float(mb & 0xFFFFFFC0u);
            int   c = (int)(mb & 63u) * 16 + lrow * 4 + rr;
            float g = __uint_as_float(__float_as_uint(m2f[pt][rr]) & 0xFFFFFFC0u);
            bool take = (f < f1) || (f == f1 && c < i1);
            float loser = take ? f1 : f;
            f2 = fminf(fminf(f2, g), loser);
            if (take) { f1 = f; i1 = c; }
        }
        F1[pt] = f1; F2[pt] = f2; I1[pt] = i1;
    }

    // ---- merge across lrow groups (4 lanes hold same position)
#pragma unroll
    for (int off = 16; off < 64; off <<= 1) {
#pragma unroll
        for (int pt = 0; pt < 2; ++pt) {
            float om1 = __shfl_xor(F1[pt], off);
            float om2 = __shfl_xor(F2[pt], off);
            int   oi  = __shfl_xor(I1[pt], off);
            bool take = (om1 < F1[pt]) || (om1 == F1[pt] && oi < I1[pt]);
            float loser = take ? F1[pt] : om1;
            F2[pt] = fminf(fminf(F2[pt], om2), loser);
            if (take) { F1[pt] = om1; I1[pt] = oi; }
        }
    }

    // ---- write idx, flag near-ties: adaptive margin (granule ~ |F1|*7.6e-6)
    if (lane < 16) {
#pragma unroll
        for (int pt = 0; pt < 2; ++pt) {
            int n = posbase + wb + pt * 16 + lane;
            idxbuf[(k << 15) + n] = I1[pt];
            float thr = fmaf(fabsf(F1[pt]), 3.2e-5f, 2.0e-3f);
            if (F2[pt] - F1[pt] < thr) {
                int slot = atomicAdd(flagcnt, 1);
                flaglist[slot] = (k << 15) + n;
            }
        }
    }
}

// ---------------------------------------------------------------- rescore v4
// One BLOCK (256 threads) per flagged position: each thread owns 4 codes
// (64 f32x4 loads, 4 independent chains). Exact fp32, first-min tie-break.
__global__ void __launch_bounds__(256) k_rescore(
        const float* __restrict__ z, const float* __restrict__ emb,
        const float* __restrict__ e2g, const int* __restrict__ flagcnt,
        const int* __restrict__ flaglist, int* __restrict__ idxbuf) {
    __shared__ __attribute__((aligned(16))) float xsh[64];
    __shared__ float wbest[4];
    __shared__ int   wbi[4];
    int tid = threadIdx.x;
    int wave = tid >> 6, lane = tid & 63;
    int nf = *flagcnt;
    for (int e = blockIdx.x; e < nf; e += gridDim.x) {
        int gp = flaglist[e];
        int kk = gp >> 15, n = gp & 32767;
        int bb = n >> 13, s = n & 8191;
        __syncthreads();                   // xsh/wbest reuse guard
        if (tid < 64)
            xsh[tid] = z[(((size_t)(bb * CCH + kk * DIM + tid)) << 13) + s];
        __syncthreads();

        const f32x4* ek4 = (const f32x4*)(emb + ((size_t)kk << 16));
        const float* ee  = e2g + (kk << 10);
        const f32x4* xr4 = (const f32x4*)xsh;
        float best = 3.4e38f; int bi = 0;
#pragma unroll
        for (int cc = 0; cc < 4; ++cc) {
            int c = cc * 256 + tid;
            const f32x4* ev = ek4 + (size_t)c * 16;
            float a0 = 0.f, a1 = 0.f, a2 = 0.f, a3 = 0.f;
#pragma unroll
            for (int j = 0; j < 16; ++j) {
                f32x4 xv = xr4[j];
                f32x4 qv = ev[j];
                a0 = fmaf(xv[0], qv[0], a0); a1 = fmaf(xv[1], qv[1], a1);
                a2 = fmaf(xv[2], qv[2], a2); a3 = fmaf(xv[3], qv[3], a3);
            }
            float dist = fmaf(-2.f, (a0 + a1) + (a2 + a3), ee[c]);
            if (dist < best) { best = dist; bi = c; }    // cc ascending => first-min
        }
#pragma unroll
        for (int off = 1; off < 64; off <<= 1) {
            float ob = __shfl_xor(best, off);
            int   oi = __shfl_xor(bi, off);
            if (ob < best || (ob == best && oi < bi)) { best = ob; bi = oi; }
        }
        if (lane == 0) { wbest[wave] = best; wbi[wave] = bi; }
        __syncthreads();
        if (tid == 0) {
            float b0 = wbest[0]; int i0 = wbi[0];
#pragma unroll
            for (int w = 1; w < 4; ++w) {
                float bw = wbest[w]; int iw = wbi[w];
                if (bw < b0 || (bw == b0 && iw < i0)) { b0 = bw; i0 = iw; }
            }
            idxbuf[gp] = i0;
        }
    }
}

// ---------------------------------------------------------------- gather+loss
// 4 consecutive positions per thread -> float4 z loads / q stores.
__global__ void __launch_bounds__(256) k_quant(
        const float* __restrict__ z, const float* __restrict__ emb,
        const int* __restrict__ idxbuf, float* __restrict__ out,
        int* __restrict__ counts, float* __restrict__ partial) {
    int tid = threadIdx.x;
    int q = blockIdx.x * 256 + tid;       // quad index
    int n0 = q * 4;
    int k = blockIdx.y;
    int b = n0 >> 13;
    int s = n0 & 8191;

    int4 bi = *(const int4*)&idxbuf[(k << 15) + n0];
    const f32x4* e0 = (const f32x4*)(emb + ((size_t)k << 16) + ((size_t)bi.x << 6));
    const f32x4* e1 = (const f32x4*)(emb + ((size_t)k << 16) + ((size_t)bi.y << 6));
    const f32x4* e2 = (const f32x4*)(emb + ((size_t)k << 16) + ((size_t)bi.z << 6));
    const f32x4* e3 = (const f32x4*)(emb + ((size_t)k << 16) + ((size_t)bi.w << 6));
    size_t base = (((size_t)(b * CCH + k * DIM)) << 13) + s;

    float sq = 0.f;
#pragma unroll
    for (int j = 0; j < 16; ++j) {
        f32x4 q0 = e0[j], q1 = e1[j], q2 = e2[j], q3 = e3[j];
#pragma unroll
        for (int i = 0; i < 4; ++i) {
            int d = j * 4 + i;
            f32x4 zv = *(const f32x4*)(z + base + ((size_t)d << 13));
            f32x4 ov = {q0[i], q1[i], q2[i], q3[i]};
            *(f32x4*)(out + base + ((size_t)d << 13)) = ov;
            f32x4 df = zv - ov;
            sq = fmaf(df[0], df[0], sq);
            sq = fmaf(df[1], df[1], sq);
            sq = fmaf(df[2], df[2], sq);
            sq = fmaf(df[3], df[3], sq);
        }
    }

    out[ENC_OFF + (size_t)(n0 + 0) * NBOOKS + k] = (float)bi.x;
    out[ENC_OFF + (size_t)(n0 + 1) * NBOOKS + k] = (float)bi.y;
    out[ENC_OFF + (size_t)(n0 + 2) * NBOOKS + k] = (float)bi.z;
    out[ENC_OFF + (size_t)(n0 + 3) * NBOOKS + k] = (float)bi.w;
    atomicAdd(&counts[(k << 10) + bi.x], 1);
    atomicAdd(&counts[(k << 10) + bi.y], 1);
    atomicAdd(&counts[(k << 10) + bi.z], 1);
    atomicAdd(&counts[(k << 10) + bi.w], 1);

    for (int off = 32; off; off >>= 1) sq += __shfl_down(sq, off, 64);
    __shared__ float red[4];
    if ((tid & 63) == 0) red[tid >> 6] = sq;
    __syncthreads();
    if (tid == 0)
        partial[blockIdx.y * gridDim.x + blockIdx.x] = (red[0] + red[1]) + (red[2] + red[3]);
}

// ---------------------------------------------------------------- finalize
__global__ void __launch_bounds__(256) k_fin(
        const int* __restrict__ counts, const float* __restrict__ partial,
        float* __restrict__ out) {
    __shared__ float sh[256];
    int tid = threadIdx.x;

    sh[tid] = tid < 128 ? partial[tid] : 0.f;   // 32 blocks x 4 books
    __syncthreads();
    for (int off = 128; off; off >>= 1) {
        if (tid < off) sh[tid] += sh[tid + off];
        __syncthreads();
    }
    if (tid == 0) out[LOSS_OFF] = 0.25f * sh[0] / 8388608.f;

    float psum = 0.f;
    for (int k = 0; k < NBOOKS; ++k) {
        float h = 0.f;
        for (int c = tid; c < CODES; c += 256) {
            float p = (float)counts[(k << 10) + c] * (1.f / 32768.f);
            h += p * logf(p + 1e-10f);
        }
        __syncthreads();
        sh[tid] = h;
        __syncthreads();
        for (int off = 128; off; off >>= 1) {
            if (tid < off) sh[tid] += sh[tid + off];
            __syncthreads();
        }
        if (tid == 0) psum += expf(-sh[0]);
        __syncthreads();
    }
    if (tid == 0) out[PERP_OFF] = psum * (1.f / NBOOKS);
}

// ----------------------------------------------------------------
extern "C" void kernel_launch(void* const* d_in, const int* in_sizes, int n_in,
                              void* d_out, int out_size, void* d_ws, size_t ws_size,
                              hipStream_t stream) {
    const float* z   = (const float*)d_in[0];
    const float* emb = (const float*)d_in[1];
    float* out = (float*)d_out;
    char* ws = (char*)d_ws;

    float*    e2       = (float*)(ws + WS_E2);
    _Float16* ehi      = (_Float16*)(ws + WS_EHI);
    _Float16* elo      = (_Float16*)(ws + WS_ELO);
    int*      idxbuf   = (int*)(ws + WS_IDX);
    int*      counts   = (int*)(ws + WS_CNT);
    float*    partial  = (float*)(ws + WS_PART);
    int*      flagcnt  = (int*)(ws + WS_FLAGCNT);
    int*      flaglist = (int*)(ws + WS_FLAGS);

    k_eprep2<<<16, 256, 0, stream>>>(emb, e2, ehi, elo, counts, flagcnt);

    dim3 agrid(NPOS / 128, NBOOKS);
    k_argmin_mfma<<<agrid, 256, 0, stream>>>(z, e2, ehi, elo, idxbuf, flagcnt, flaglist);
    k_rescore<<<1024, 256, 0, stream>>>(z, emb, e2, flagcnt, flaglist, idxbuf);

    dim3 qgrid(NPOS / 1024, NBOOKS);
    k_quant<<<qgrid, 256, 0, stream>>>(z, emb, idxbuf, out, counts, partial);
    k_fin<<<1, 256, 0, stream>>>(counts, partial, out);
}

// Round 12
// 113.913 us; speedup vs baseline: 1.0586x; 1.0586x over previous
//
#include <hip/hip_runtime.h>

// Problem constants
#define NBOOKS 4
#define CODES  1024
#define DIM    64
#define NPOS   32768          // B*T*H*W
#define CCH    256            // NB*DIM (channel dim of z)
#define ENC_OFF  8388608
#define LOSS_OFF 8519680
#define PERP_OFF 8519681

// workspace byte offsets
#define WS_E2      0              // 4096 f32 (raw ||e||^2)
#define WS_EHI     16384          // 4096*64 f16 = 512 KB  (hi of -2*e)
#define WS_ELO     540672         // 512 KB                 (lo of -2*e)
#define WS_IDX     1064960        // 131072 int
#define WS_CNT     1589248        // 4096 int
#define WS_PART    1605632        // 128 f32
#define WS_FLAGCNT 1607680        // 1 int
#define WS_FLAGS   1607696        // 131072 int

typedef _Float16 f16x8 __attribute__((ext_vector_type(8)));
typedef _Float16 f16x4 __attribute__((ext_vector_type(4)));
typedef float    f32x4 __attribute__((ext_vector_type(4)));

// ------------------------------------------- prep: e2, hi/lo f16(-2e), zeroing
__global__ void k_eprep2(const float* __restrict__ emb, float* __restrict__ e2,
                         _Float16* __restrict__ ehi, _Float16* __restrict__ elo,
                         int* __restrict__ counts, int* __restrict__ flagcnt) {
    int i = blockIdx.x * 256 + threadIdx.x;            // row 0..4095 = k*1024+c
    counts[i] = 0;
    if (i == 0) *flagcnt = 0;
    const float4* e = (const float4*)(emb + ((size_t)i << 6));
    _Float16* hp = ehi + ((size_t)i << 6);
    _Float16* lp = elo + ((size_t)i << 6);
    float s = 0.f;
#pragma unroll
    for (int j = 0; j < 16; ++j) {
        float4 v = e[j];
        s += v.x * v.x + v.y * v.y + v.z * v.z + v.w * v.w;
        f16x4 hv, lv;
        float m;
        m = -2.f * v.x; hv[0] = (_Float16)m; lv[0] = (_Float16)(m - (float)hv[0]);
        m = -2.f * v.y; hv[1] = (_Float16)m; lv[1] = (_Float16)(m - (float)hv[1]);
        m = -2.f * v.z; hv[2] = (_Float16)m; lv[2] = (_Float16)(m - (float)hv[2]);
        m = -2.f * v.w; hv[3] = (_Float16)m; lv[3] = (_Float16)(m - (float)hv[3]);
        *(f16x4*)&hp[j * 4] = hv;
        *(f16x4*)&lp[j * 4] = lv;
    }
    e2[i] = s;           // raw ||e||^2; score = e2 - 2x.e (may be negative: ok)
}

// ---------------------------------------------------------------- MFMA argmin v8
// Block = 128 positions x all 1024 codes, one book; 4 waves x 32 pos each,
// 4 blocks/CU. X direct global->regs. acc init = e2v (raw); float-domain
// tracking (negatives ordered correctly; equal-truncation ties always flagged).
// Per chunk: barrier -> ds_read current frags -> ISSUE next-chunk global
// prefetch -> 24 MFMA (hides prefetch latency) -> ds_write next -> rotate.
// (Prefetch issued AFTER the barrier so the compiler's vmcnt(0)-before-barrier
//  drain no longer exposes L2 latency every chunk.)
__global__ void __launch_bounds__(256, 4) k_argmin_mfma(
        const float* __restrict__ z, const float* __restrict__ e2g,
        const _Float16* __restrict__ ehi, const _Float16* __restrict__ elo,
        int* __restrict__ idxbuf, int* __restrict__ flagcnt,
        int* __restrict__ flaglist) {
    __shared__ __attribute__((aligned(16))) char sE[3][8192];  // hi[0,4K) lo[4K,8K)

    int tid = threadIdx.x;
    int wave = tid >> 6, lane = tid & 63;
    int lrow = lane >> 4, lcol = lane & 15;
    int k = blockIdx.y;
    int posbase = blockIdx.x * 128;
    int b = posbase >> 13, s0 = posbase & 8191;
    int wb = wave * 32;

    // ---- X fragments straight into registers
    const float* zb = z + (((size_t)(b * CCH + k * DIM)) << 13) + s0 + wb;
    f16x8 Xh[2][2], Xl[2][2];
#pragma unroll
    for (int pt = 0; pt < 2; ++pt)
#pragma unroll
        for (int kc = 0; kc < 2; ++kc) {
            f16x8 hv, lv;
#pragma unroll
            for (int e = 0; e < 8; ++e) {
                int d = kc * 32 + lrow * 8 + e;
                float f = zb[((size_t)d << 13) + pt * 16 + lcol];
                _Float16 h = (_Float16)f;
                hv[e] = h;
                lv[e] = (_Float16)(f - (float)h);
            }
            Xh[pt][kc] = hv; Xl[pt][kc] = lv;
        }

    // ---- E staging params: thread moves 32 B (two swizzled 16B pieces)/chunk
    int half = tid >> 7;                  // 0: hi, 1: lo
    int u = tid & 127;
    int r = u >> 2, q = u & 3;            // code row 0..31, 32B quarter 0..3
    const char* bookh = (const char*)((half ? elo : ehi) + ((size_t)k << 16));
    const char* src0 = bookh + r * 128 + q * 32;          // + chunk*4096
    int c0 = 2 * q, c1 = 2 * q + 1;
    int w0 = half * 4096 + r * 128 + ((c0 ^ (r & 7)) << 4);
    int w1 = half * 4096 + r * 128 + ((c1 ^ (r & 7)) << 4);

    const float* e2p = e2g + (k << 10) + lrow * 4;

    // prologue: stage chunk 0 into buffer 0; load chunk-0 e2 vectors
    {
        f16x8 v0 = *(const f16x8*)(src0);
        f16x8 v1 = *(const f16x8*)(src0 + 16);
        *(f16x8*)&sE[0][w0] = v0;
        *(f16x8*)&sE[0][w1] = v1;
    }
    f32x4 ce2a = *(const f32x4*)(e2p);
    f32x4 ce2b = *(const f32x4*)(e2p + 16);

    float m1f[2][4], m2f[2][4];
#pragma unroll
    for (int pt = 0; pt < 2; ++pt)
#pragma unroll
        for (int rr = 0; rr < 4; ++rr) { m1f[pt][rr] = 3.4e38f; m2f[pt][rr] = 3.4e38f; }

    int sx = (lcol & 7) << 4;
    int o0 = (lrow << 4) ^ sx;            // K-chunk 0 (dims 0..31)
    int o1 = ((4 + lrow) << 4) ^ sx;      // K-chunk 1 (dims 32..63)
    int rbase = lcol << 7;                // code row stride 128 B (+ st*2048)

    int cur = 0, nxt = 1, fre = 2;
    for (int it = 0; it < 32; ++it) {
        __syncthreads();                  // buffer cur ready; vmcnt already 0
        const char* sc = sE[cur];

        // ---- ds_read ALL current-chunk fragments (both st halves)
        const char* rb0 = sc + rbase;
        const char* rb1 = sc + 2048 + rbase;
        f16x8 eh0a = *(const f16x8*)(rb0 + o0);
        f16x8 eh1a = *(const f16x8*)(rb0 + o1);
        f16x8 el0a = *(const f16x8*)(rb0 + 4096 + o0);
        f16x8 el1a = *(const f16x8*)(rb0 + 4096 + o1);
        f16x8 eh0b = *(const f16x8*)(rb1 + o0);
        f16x8 eh1b = *(const f16x8*)(rb1 + o1);
        f16x8 el0b = *(const f16x8*)(rb1 + 4096 + o0);
        f16x8 el1b = *(const f16x8*)(rb1 + 4096 + o1);

        // ---- issue next-chunk global prefetch (lands during MFMAs)
        f16x8 nv0, nv1;
        f32x4 ne2a, ne2b;
        bool has = it < 31;
        if (has) {
            const char* sp = src0 + (size_t)(it + 1) * 4096;
            nv0 = *(const f16x8*)(sp);
            nv1 = *(const f16x8*)(sp + 16);
            ne2a = *(const f32x4*)(e2p + (it + 1) * 32);
            ne2b = *(const f32x4*)(e2p + (it + 1) * 32 + 16);
        }

        // ---- MFMA + tracking, st = 0 then 1
#pragma unroll
        for (int st = 0; st < 2; ++st) {
            f16x8 eh0 = st ? eh0b : eh0a;
            f16x8 eh1 = st ? eh1b : eh1a;
            f16x8 el0 = st ? el0b : el0a;
            f16x8 el1 = st ? el1b : el1a;
            f32x4 e2v = st ? ce2b : ce2a;
            unsigned kit = (unsigned)(it * 2 + st);
#pragma unroll
            for (int pt = 0; pt < 2; ++pt) {
                f32x4 acc = e2v;          // score = ||e||^2 - 2x.e (sign ok)
                acc = __builtin_amdgcn_mfma_f32_16x16x32_f16(eh0, Xh[pt][0], acc, 0, 0, 0);
                acc = __builtin_amdgcn_mfma_f32_16x16x32_f16(eh0, Xl[pt][0], acc, 0, 0, 0);
                acc = __builtin_amdgcn_mfma_f32_16x16x32_f16(el0, Xh[pt][0], acc, 0, 0, 0);
                acc = __builtin_amdgcn_mfma_f32_16x16x32_f16(eh1, Xh[pt][1], acc, 0, 0, 0);
                acc = __builtin_amdgcn_mfma_f32_16x16x32_f16(eh1, Xl[pt][1], acc, 0, 0, 0);
                acc = __builtin_amdgcn_mfma_f32_16x16x32_f16(el1, Xh[pt][1], acc, 0, 0, 0);
#pragma unroll
                for (int rr = 0; rr < 4; ++rr) {
                    float key = __uint_as_float(
                        (__float_as_uint(acc[rr]) & 0xFFFFFFC0u) | kit);
                    m2f[pt][rr] = __builtin_amdgcn_fmed3f(m1f[pt][rr], m2f[pt][rr], key);
                    m1f[pt][rr] = fminf(m1f[pt][rr], key);
                }
            }
        }

        // ---- write next chunk to LDS (vmcnt wait lands here, after MFMAs)
        if (has) {
            *(f16x8*)&sE[nxt][w0] = nv0;
            *(f16x8*)&sE[nxt][w1] = nv1;
            ce2a = ne2a; ce2b = ne2b;
        }
        int t = cur; cur = nxt; nxt = fre; fre = t;
    }

    // ---- within-thread merge over r slots (exact, index tie-break)
    float F1[2], F2[2]; int I1[2];
#pragma unroll
    for (int pt = 0; pt < 2; ++pt) {
        float f1 = 3.4e38f, f2 = 3.4e38f; int i1 = 0;
#pragma unroll
        for (int rr = 0; rr < 4; ++rr) {
            unsigned mb = __float_as_uint(m1f[pt][rr]);
            float f = __uint_as_float(mb & 0xFFFFFFC0u);
            int   c = (int)(mb & 63u) * 16 + lrow * 4 + rr;
            float g = __uint_as_float(__float_as_uint(m2f[pt][rr]) & 0xFFFFFFC0u);
            bool take = (f < f1) || (f == f1 && c < i1);
            float loser = take ? f1 : f;
            f2 = fminf(fminf(f2, g), loser);
            if (take) { f1 = f; i1 = c; }
        }
        F1[pt] = f1; F2[pt] = f2; I1[pt] = i1;
    }

    // ---- merge across lrow groups (4 lanes hold same position)
#pragma unroll
    for (int off = 16; off < 64; off <<= 1) {
#pragma unroll
        for (int pt = 0; pt < 2; ++pt) {
            float om1 = __shfl_xor(F1[pt], off);
            float om2 = __shfl_xor(F2[pt], off);
            int   oi  = __shfl_xor(I1[pt], off);
            bool take = (om1 < F1[pt]) || (om1 == F1[pt] && oi < I1[pt]);
            float loser = take ? F1[pt] : om1;
            F2[pt] = fminf(fminf(F2[pt], om2), loser);
            if (take) { F1[pt] = om1; I1[pt] = oi; }
        }
    }

    // ---- write idx, flag near-ties: adaptive margin (granule ~ |F1|*7.6e-6)
    if (lane < 16) {
#pragma unroll
        for (int pt = 0; pt < 2; ++pt) {
            int n = posbase + wb + pt * 16 + lane;
            idxbuf[(k << 15) + n] = I1[pt];
            float thr = fmaf(fabsf(F1[pt]), 3.2e-5f, 2.0e-3f);
            if (F2[pt] - F1[pt] < thr) {
                int slot = atomicAdd(flagcnt, 1);
                flaglist[slot] = (k << 15) + n;
            }
        }
    }
}

// ---------------------------------------------------------------- rescore v4
// One BLOCK (256 threads) per flagged position: each thread owns 4 codes
// (64 f32x4 loads, 4 independent chains). Exact fp32, first-min tie-break.
__global__ void __launch_bounds__(256) k_rescore(
        const float* __restrict__ z, const float* __restrict__ emb,
        const float* __restrict__ e2g, const int* __restrict__ flagcnt,
        const int* __restrict__ flaglist, int* __restrict__ idxbuf) {
    __shared__ __attribute__((aligned(16))) float xsh[64];
    __shared__ float wbest[4];
    __shared__ int   wbi[4];
    int tid = threadIdx.x;
    int wave = tid >> 6, lane = tid & 63;
    int nf = *flagcnt;
    for (int e = blockIdx.x; e < nf; e += gridDim.x) {
        int gp = flaglist[e];
        int kk = gp >> 15, n = gp & 32767;
        int bb = n >> 13, s = n & 8191;
        __syncthreads();                   // xsh/wbest reuse guard
        if (tid < 64)
            xsh[tid] = z[(((size_t)(bb * CCH + kk * DIM + tid)) << 13) + s];
        __syncthreads();

        const f32x4* ek4 = (const f32x4*)(emb + ((size_t)kk << 16));
        const float* ee  = e2g + (kk << 10);
        const f32x4* xr4 = (const f32x4*)xsh;
        float best = 3.4e38f; int bi = 0;
#pragma unroll
        for (int cc = 0; cc < 4; ++cc) {
            int c = cc * 256 + tid;
            const f32x4* ev = ek4 + (size_t)c * 16;
            float a0 = 0.f, a1 = 0.f, a2 = 0.f, a3 = 0.f;
#pragma unroll
            for (int j = 0; j < 16; ++j) {
                f32x4 xv = xr4[j];
                f32x4 qv = ev[j];
                a0 = fmaf(xv[0], qv[0], a0); a1 = fmaf(xv[1], qv[1], a1);
                a2 = fmaf(xv[2], qv[2], a2); a3 = fmaf(xv[3], qv[3], a3);
            }
            float dist = fmaf(-2.f, (a0 + a1) + (a2 + a3), ee[c]);
            if (dist < best) { best = dist; bi = c; }    // cc ascending => first-min
        }
#pragma unroll
        for (int off = 1; off < 64; off <<= 1) {
            float ob = __shfl_xor(best, off);
            int   oi = __shfl_xor(bi, off);
            if (ob < best || (ob == best && oi < bi)) { best = ob; bi = oi; }
        }
        if (lane == 0) { wbest[wave] = best; wbi[wave] = bi; }
        __syncthreads();
        if (tid == 0) {
            float b0 = wbest[0]; int i0 = wbi[0];
#pragma unroll
            for (int w = 1; w < 4; ++w) {
                float bw = wbest[w]; int iw = wbi[w];
                if (bw < b0 || (bw == b0 && iw < i0)) { b0 = bw; i0 = iw; }
            }
            idxbuf[gp] = i0;
        }
    }
}

// ---------------------------------------------------------------- gather+loss
// 4 consecutive positions per thread -> float4 z loads / q stores.
__global__ void __launch_bounds__(256) k_quant(
        const float* __restrict__ z, const float* __restrict__ emb,
        const int* __restrict__ idxbuf, float* __restrict__ out,
        int* __restrict__ counts, float* __restrict__ partial) {
    int tid = threadIdx.x;
    int q = blockIdx.x * 256 + tid;       // quad index
    int n0 = q * 4;
    int k = blockIdx.y;
    int b = n0 >> 13;
    int s = n0 & 8191;

    int4 bi = *(const int4*)&idxbuf[(k << 15) + n0];
    const f32x4* e0 = (const f32x4*)(emb + ((size_t)k << 16) + ((size_t)bi.x << 6));
    const f32x4* e1 = (const f32x4*)(emb + ((size_t)k << 16) + ((size_t)bi.y << 6));
    const f32x4* e2 = (const f32x4*)(emb + ((size_t)k << 16) + ((size_t)bi.z << 6));
    const f32x4* e3 = (const f32x4*)(emb + ((size_t)k << 16) + ((size_t)bi.w << 6));
    size_t base = (((size_t)(b * CCH + k * DIM)) << 13) + s;

    float sq = 0.f;
#pragma unroll
    for (int j = 0; j < 16; ++j) {
        f32x4 q0 = e0[j], q1 = e1[j], q2 = e2[j], q3 = e3[j];
#pragma unroll
        for (int i = 0; i < 4; ++i) {
            int d = j * 4 + i;
            f32x4 zv = *(const f32x4*)(z + base + ((size_t)d << 13));
            f32x4 ov = {q0[i], q1[i], q2[i], q3[i]};
            *(f32x4*)(out + base + ((size_t)d << 13)) = ov;
            f32x4 df = zv - ov;
            sq = fmaf(df[0], df[0], sq);
            sq = fmaf(df[1], df[1], sq);
            sq = fmaf(df[2], df[2], sq);
            sq = fmaf(df[3], df[3], sq);
        }
    }

    out[ENC_OFF + (size_t)(n0 + 0) * NBOOKS + k] = (float)bi.x;
    out[ENC_OFF + (size_t)(n0 + 1) * NBOOKS + k] = (float)bi.y;
    out[ENC_OFF + (size_t)(n0 + 2) * NBOOKS + k] = (float)bi.z;
    out[ENC_OFF + (size_t)(n0 + 3) * NBOOKS + k] = (float)bi.w;
    atomicAdd(&counts[(k << 10) + bi.x], 1);
    atomicAdd(&counts[(k << 10) + bi.y], 1);
    atomicAdd(&counts[(k << 10) + bi.z], 1);
    atomicAdd(&counts[(k << 10) + bi.w], 1);

    for (int off = 32; off; off >>= 1) sq += __shfl_down(sq, off, 64);
    __shared__ float red[4];
    if ((tid & 63) == 0) red[tid >> 6] = sq;
    __syncthreads();
    if (tid == 0)
        partial[blockIdx.y * gridDim.x + blockIdx.x] = (red[0] + red[1]) + (red[2] + red[3]);
}

// ---------------------------------------------------------------- finalize v2
// Wave w <-> book w for perplexity (shfl reduce, no barrier); loss via one
// block-wide shfl reduction of the 128 partials. 2 barriers total.
__global__ void __launch_bounds__(256) k_fin(
        const int* __restrict__ counts, const float* __restrict__ partial,
        float* __restrict__ out) {
    __shared__ float shl[4];
    __shared__ float shp[4];
    int tid = threadIdx.x;
    int wave = tid >> 6, lane = tid & 63;

    // loss: 128 partials (32 blocks x 4 books)
    float s = tid < 128 ? partial[tid] : 0.f;
    for (int off = 32; off; off >>= 1) s += __shfl_down(s, off, 64);
    if (lane == 0) shl[wave] = s;

    // perplexity: wave w handles book w, lane handles 16 codes
    float h = 0.f;
    const int* ck = counts + (wave << 10) + lane * 16;
#pragma unroll
    for (int j = 0; j < 16; ++j) {
        float p = (float)ck[j] * (1.f / 32768.f);
        h += p * logf(p + 1e-10f);
    }
    for (int off = 32; off; off >>= 1) h += __shfl_down(h, off, 64);
    if (lane == 0) shp[wave] = expf(-h);
    __syncthreads();
    if (tid == 0) {
        out[LOSS_OFF] = 0.25f * ((shl[0] + shl[1]) + (shl[2] + shl[3])) / 8388608.f;
        out[PERP_OFF] = 0.25f * ((shp[0] + shp[1]) + (shp[2] + shp[3]));
    }
}

// ----------------------------------------------------------------
extern "C" void kernel_launch(void* const* d_in, const int* in_sizes, int n_in,
                              void* d_out, int out_size, void* d_ws, size_t ws_size,
                              hipStream_t stream) {
    const float* z   = (const float*)d_in[0];
    const float* emb = (const float*)d_in[1];
    float* out = (float*)d_out;
    char* ws = (char*)d_ws;

    float*    e2       = (float*)(ws + WS_E2);
    _Float16* ehi      = (_Float16*)(ws + WS_EHI);
    _Float16* elo      = (_Float16*)(ws + WS_ELO);
    int*      idxbuf   = (int*)(ws + WS_IDX);
    int*      counts   = (int*)(ws + WS_CNT);
    float*    partial  = (float*)(ws + WS_PART);
    int*      flagcnt  = (int*)(ws + WS_FLAGCNT);
    int*      flaglist = (int*)(ws + WS_FLAGS);

    k_eprep2<<<16, 256, 0, stream>>>(emb, e2, ehi, elo, counts, flagcnt);

    dim3 agrid(NPOS / 128, NBOOKS);
    k_argmin_mfma<<<agrid, 256, 0, stream>>>(z, e2, ehi, elo, idxbuf, flagcnt, flaglist);
    k_rescore<<<1024, 256, 0, stream>>>(z, emb, e2, flagcnt, flaglist, idxbuf);

    dim3 qgrid(NPOS / 1024, NBOOKS);
    k_quant<<<qgrid, 256, 0, stream>>>(z, emb, idxbuf, out, counts, partial);
    k_fin<<<1, 256, 0, stream>>>(counts, partial, out);
}

// Round 13
// 113.076 us; speedup vs baseline: 1.0664x; 1.0074x over previous
//
#include <hip/hip_runtime.h>

// Problem constants
#define NBOOKS 4
#define CODES  1024
#define DIM    64
#define NPOS   32768          // B*T*H*W
#define CCH    256            // NB*DIM (channel dim of z)
#define ENC_OFF  8388608
#define LOSS_OFF 8519680
#define PERP_OFF 8519681

// workspace byte offsets
#define WS_E2      0              // 4096 f32 (raw ||e||^2)
#define WS_EHI     16384          // 4096*64 f16 = 512 KB  (hi of -2*e)
#define WS_ELO     540672         // 512 KB                 (lo of -2*e)
#define WS_IDX     1064960        // 131072 int
#define WS_CNT     1589248        // 4096 int
#define WS_PART    1605632        // 128 f32
#define WS_FLAGCNT 1607680        // 1 int
#define WS_FLAGS   1607696        // 131072 int

typedef _Float16 f16x8 __attribute__((ext_vector_type(8)));
typedef _Float16 f16x4 __attribute__((ext_vector_type(4)));
typedef float    f32x4 __attribute__((ext_vector_type(4)));

// ------------------------------------------- prep: e2, hi/lo f16(-2e), zeroing
__global__ void k_eprep2(const float* __restrict__ emb, float* __restrict__ e2,
                         _Float16* __restrict__ ehi, _Float16* __restrict__ elo,
                         int* __restrict__ counts, int* __restrict__ flagcnt) {
    int i = blockIdx.x * 256 + threadIdx.x;            // row 0..4095 = k*1024+c
    counts[i] = 0;
    if (i == 0) *flagcnt = 0;
    const float4* e = (const float4*)(emb + ((size_t)i << 6));
    _Float16* hp = ehi + ((size_t)i << 6);
    _Float16* lp = elo + ((size_t)i << 6);
    float s = 0.f;
#pragma unroll
    for (int j = 0; j < 16; ++j) {
        float4 v = e[j];
        s += v.x * v.x + v.y * v.y + v.z * v.z + v.w * v.w;
        f16x4 hv, lv;
        float m;
        m = -2.f * v.x; hv[0] = (_Float16)m; lv[0] = (_Float16)(m - (float)hv[0]);
        m = -2.f * v.y; hv[1] = (_Float16)m; lv[1] = (_Float16)(m - (float)hv[1]);
        m = -2.f * v.z; hv[2] = (_Float16)m; lv[2] = (_Float16)(m - (float)hv[2]);
        m = -2.f * v.w; hv[3] = (_Float16)m; lv[3] = (_Float16)(m - (float)hv[3]);
        *(f16x4*)&hp[j * 4] = hv;
        *(f16x4*)&lp[j * 4] = lv;
    }
    e2[i] = s;           // raw ||e||^2; score = e2 - 2x.e (may be negative: ok)
}

// ---------------------------------------------------------------- MFMA argmin v9
// BARRIER-FREE main loop. Block = 128 positions, 4 waves; wave w owns codes
// [256w, 256w+256) and covers ALL 128 positions. X fragments: direct
// global->regs (128 VGPR, no LDS copy -> no remat, no spill source).
// E fragments: read straight from L2 (slice private to wave), reg
// double-buffered; acc init = e2 (raw; float-domain ordering handles sign).
// Tracking: key = (score_bits & ~63)|(at*4+rr); m1 per (bt,rr) via fmin;
// m2 per bt via fmed3 (exact second-min: displaced m1 values captured by
// med3, cross-slot seconds captured by other m1 slots).
// One barrier total: cross-wave merge of (F1,F2,I1) through 6 KB LDS.
__global__ void __launch_bounds__(256, 2) k_argmin_mfma(
        const float* __restrict__ z, const float* __restrict__ e2g,
        const _Float16* __restrict__ ehi, const _Float16* __restrict__ elo,
        int* __restrict__ idxbuf, int* __restrict__ flagcnt,
        int* __restrict__ flaglist) {
    __shared__ float sF1[512];
    __shared__ float sF2[512];
    __shared__ int   sI1[512];

    int tid = threadIdx.x;
    int wave = tid >> 6, lane = tid & 63;
    int lrow = lane >> 4, lcol = lane & 15;
    int k = blockIdx.y;
    int posbase = blockIdx.x * 128;
    int b = posbase >> 13, s0 = posbase & 8191;

    // ---- X fragments for ALL 128 positions straight into registers
    const float* zb = z + (((size_t)(b * CCH + k * DIM)) << 13) + s0;
    f16x8 Xh[8][2], Xl[8][2];
#pragma unroll
    for (int bt = 0; bt < 8; ++bt)
#pragma unroll
        for (int kc = 0; kc < 2; ++kc) {
            f16x8 hv, lv;
#pragma unroll
            for (int e = 0; e < 8; ++e) {
                int d = kc * 32 + lrow * 8 + e;
                float f = zb[((size_t)d << 13) + bt * 16 + lcol];
                _Float16 h = (_Float16)f;
                hv[e] = h;
                lv[e] = (_Float16)(f - (float)h);
            }
            Xh[bt][kc] = hv; Xl[bt][kc] = lv;
        }

    // ---- E slice pointers (wave-private 256 codes; same fragment layout as
    //      the proven LDS version, source is L2 instead)
    int slice = wave << 8;                 // first code of this wave's slice
    const _Float16* ehp = ehi + ((size_t)k << 16) + (size_t)(slice + lcol) * 64 + lrow * 8;
    const _Float16* elp = elo + ((size_t)k << 16) + (size_t)(slice + lcol) * 64 + lrow * 8;
    const float*    e2p = e2g + (k << 10) + slice + lrow * 4;

    // prologue: at=0 fragments
    f16x8 ceh0 = *(const f16x8*)(ehp);
    f16x8 ceh1 = *(const f16x8*)(ehp + 32);
    f16x8 cel0 = *(const f16x8*)(elp);
    f16x8 cel1 = *(const f16x8*)(elp + 32);
    f32x4 ce2  = *(const f32x4*)(e2p);

    float m1[8][4], m2[8];
#pragma unroll
    for (int bt = 0; bt < 8; ++bt) {
        m2[bt] = 3.4e38f;
#pragma unroll
        for (int rr = 0; rr < 4; ++rr) m1[bt][rr] = 3.4e38f;
    }

    for (int at = 0; at < 16; ++at) {
        // prefetch next code-tile fragments (reg double-buffer, no barrier)
        f16x8 neh0, neh1, nel0, nel1;
        f32x4 ne2;
        bool has = at < 15;
        if (has) {
            const _Float16* nh = ehp + (at + 1) * 1024;
            const _Float16* nl = elp + (at + 1) * 1024;
            neh0 = *(const f16x8*)(nh);
            neh1 = *(const f16x8*)(nh + 32);
            nel0 = *(const f16x8*)(nl);
            nel1 = *(const f16x8*)(nl + 32);
            ne2  = *(const f32x4*)(e2p + (at + 1) * 16);
        }

        unsigned kbase = (unsigned)(at * 4);
#pragma unroll
        for (int bt = 0; bt < 8; ++bt) {
            f32x4 acc = ce2;               // score = ||e||^2 - 2x.e
            acc = __builtin_amdgcn_mfma_f32_16x16x32_f16(ceh0, Xh[bt][0], acc, 0, 0, 0);
            acc = __builtin_amdgcn_mfma_f32_16x16x32_f16(ceh0, Xl[bt][0], acc, 0, 0, 0);
            acc = __builtin_amdgcn_mfma_f32_16x16x32_f16(cel0, Xh[bt][0], acc, 0, 0, 0);
            acc = __builtin_amdgcn_mfma_f32_16x16x32_f16(ceh1, Xh[bt][1], acc, 0, 0, 0);
            acc = __builtin_amdgcn_mfma_f32_16x16x32_f16(ceh1, Xl[bt][1], acc, 0, 0, 0);
            acc = __builtin_amdgcn_mfma_f32_16x16x32_f16(cel1, Xh[bt][1], acc, 0, 0, 0);
#pragma unroll
            for (int rr = 0; rr < 4; ++rr) {
                float key = __uint_as_float(
                    (__float_as_uint(acc[rr]) & 0xFFFFFFC0u) | (kbase + (unsigned)rr));
                m2[bt]     = __builtin_amdgcn_fmed3f(m1[bt][rr], m2[bt], key);
                m1[bt][rr] = fminf(m1[bt][rr], key);
            }
        }
        if (has) {
            ceh0 = neh0; ceh1 = neh1; cel0 = nel0; cel1 = nel1; ce2 = ne2;
        }
    }

    // ---- per-bt fold: F1 = min over rr (packed bits give first-min
    //      tie-break: key order == code order within a lane); F2 exact.
#pragma unroll
    for (int bt = 0; bt < 8; ++bt) {
        float a = m1[bt][0], bb2 = m1[bt][1], c = m1[bt][2], d = m1[bt][3];
        float min01 = fminf(a, bb2), min23 = fminf(c, d);
        float max01 = fmaxf(a, bb2), max23 = fmaxf(c, d);
        float f1 = fminf(min01, min23);
        float s2q = fminf(fmaxf(min01, min23), fminf(max01, max23));
        float f2 = fminf(m2[bt], s2q);

        unsigned mb = __float_as_uint(f1);
        unsigned lm = mb & 63u;
        int I1 = slice + (int)(lm >> 2) * 16 + lrow * 4 + (int)(lm & 3u);
        float F1 = __uint_as_float(mb & 0xFFFFFFC0u);
        float F2 = __uint_as_float(__float_as_uint(f2) & 0xFFFFFFC0u);

        // merge across lrow groups (4 lanes hold same position)
#pragma unroll
        for (int off = 16; off < 64; off <<= 1) {
            float om1 = __shfl_xor(F1, off);
            float om2 = __shfl_xor(F2, off);
            int   oi  = __shfl_xor(I1, off);
            bool take = (om1 < F1) || (om1 == F1 && oi < I1);
            float loser = take ? F1 : om1;
            F2 = fminf(fminf(F2, om2), loser);
            if (take) { F1 = om1; I1 = oi; }
        }
        if (lane < 16) {
            int p = bt * 16 + lane;
            sF1[wave * 128 + p] = F1;
            sF2[wave * 128 + p] = F2;
            sI1[wave * 128 + p] = I1;
        }
    }
    __syncthreads();

    // ---- merge the 4 wave slices, write idx, flag near-ties
    if (tid < 128) {
        float a1 = sF1[tid], a2 = sF2[tid];
        int   ai = sI1[tid];
#pragma unroll
        for (int w = 1; w < 4; ++w) {
            float b1 = sF1[w * 128 + tid], b2 = sF2[w * 128 + tid];
            int   bi = sI1[w * 128 + tid];
            bool take = (b1 < a1) || (b1 == a1 && bi < ai);
            float loser = take ? a1 : b1;
            a2 = fminf(fminf(a2, b2), loser);
            if (take) { a1 = b1; ai = bi; }
        }
        int n = posbase + tid;
        idxbuf[(k << 15) + n] = ai;
        float thr = fmaf(fabsf(a1), 1.6e-5f, 1.2e-3f);
        if (a2 - a1 < thr) {
            int slot = atomicAdd(flagcnt, 1);
            flaglist[slot] = (k << 15) + n;
        }
    }
}

// ---------------------------------------------------------------- rescore v4
// One BLOCK (256 threads) per flagged position: each thread owns 4 codes
// (64 f32x4 loads, 4 independent chains). Exact fp32, first-min tie-break.
__global__ void __launch_bounds__(256) k_rescore(
        const float* __restrict__ z, const float* __restrict__ emb,
        const float* __restrict__ e2g, const int* __restrict__ flagcnt,
        const int* __restrict__ flaglist, int* __restrict__ idxbuf) {
    __shared__ __attribute__((aligned(16))) float xsh[64];
    __shared__ float wbest[4];
    __shared__ int   wbi[4];
    int tid = threadIdx.x;
    int wave = tid >> 6, lane = tid & 63;
    int nf = *flagcnt;
    for (int e = blockIdx.x; e < nf; e += gridDim.x) {
        int gp = flaglist[e];
        int kk = gp >> 15, n = gp & 32767;
        int bb = n >> 13, s = n & 8191;
        __syncthreads();                   // xsh/wbest reuse guard
        if (tid < 64)
            xsh[tid] = z[(((size_t)(bb * CCH + kk * DIM + tid)) << 13) + s];
        __syncthreads();

        const f32x4* ek4 = (const f32x4*)(emb + ((size_t)kk << 16));
        const float* ee  = e2g + (kk << 10);
        const f32x4* xr4 = (const f32x4*)xsh;
        float best = 3.4e38f; int bi = 0;
#pragma unroll
        for (int cc = 0; cc < 4; ++cc) {
            int c = cc * 256 + tid;
            const f32x4* ev = ek4 + (size_t)c * 16;
            float a0 = 0.f, a1 = 0.f, a2 = 0.f, a3 = 0.f;
#pragma unroll
            for (int j = 0; j < 16; ++j) {
                f32x4 xv = xr4[j];
                f32x4 qv = ev[j];
                a0 = fmaf(xv[0], qv[0], a0); a1 = fmaf(xv[1], qv[1], a1);
                a2 = fmaf(xv[2], qv[2], a2); a3 = fmaf(xv[3], qv[3], a3);
            }
            float dist = fmaf(-2.f, (a0 + a1) + (a2 + a3), ee[c]);
            if (dist < best) { best = dist; bi = c; }    // cc ascending => first-min
        }
#pragma unroll
        for (int off = 1; off < 64; off <<= 1) {
            float ob = __shfl_xor(best, off);
            int   oi = __shfl_xor(bi, off);
            if (ob < best || (ob == best && oi < bi)) { best = ob; bi = oi; }
        }
        if (lane == 0) { wbest[wave] = best; wbi[wave] = bi; }
        __syncthreads();
        if (tid == 0) {
            float b0 = wbest[0]; int i0 = wbi[0];
#pragma unroll
            for (int w = 1; w < 4; ++w) {
                float bw = wbest[w]; int iw = wbi[w];
                if (bw < b0 || (bw == b0 && iw < i0)) { b0 = bw; i0 = iw; }
            }
            idxbuf[gp] = i0;
        }
    }
}

// ---------------------------------------------------------------- gather+loss
// 4 consecutive positions per thread -> float4 z loads / q stores.
__global__ void __launch_bounds__(256) k_quant(
        const float* __restrict__ z, const float* __restrict__ emb,
        const int* __restrict__ idxbuf, float* __restrict__ out,
        int* __restrict__ counts, float* __restrict__ partial) {
    int tid = threadIdx.x;
    int q = blockIdx.x * 256 + tid;       // quad index
    int n0 = q * 4;
    int k = blockIdx.y;
    int b = n0 >> 13;
    int s = n0 & 8191;

    int4 bi = *(const int4*)&idxbuf[(k << 15) + n0];
    const f32x4* e0 = (const f32x4*)(emb + ((size_t)k << 16) + ((size_t)bi.x << 6));
    const f32x4* e1 = (const f32x4*)(emb + ((size_t)k << 16) + ((size_t)bi.y << 6));
    const f32x4* e2 = (const f32x4*)(emb + ((size_t)k << 16) + ((size_t)bi.z << 6));
    const f32x4* e3 = (const f32x4*)(emb + ((size_t)k << 16) + ((size_t)bi.w << 6));
    size_t base = (((size_t)(b * CCH + k * DIM)) << 13) + s;

    float sq = 0.f;
#pragma unroll
    for (int j = 0; j < 16; ++j) {
        f32x4 q0 = e0[j], q1 = e1[j], q2 = e2[j], q3 = e3[j];
#pragma unroll
        for (int i = 0; i < 4; ++i) {
            int d = j * 4 + i;
            f32x4 zv = *(const f32x4*)(z + base + ((size_t)d << 13));
            f32x4 ov = {q0[i], q1[i], q2[i], q3[i]};
            *(f32x4*)(out + base + ((size_t)d << 13)) = ov;
            f32x4 df = zv - ov;
            sq = fmaf(df[0], df[0], sq);
            sq = fmaf(df[1], df[1], sq);
            sq = fmaf(df[2], df[2], sq);
            sq = fmaf(df[3], df[3], sq);
        }
    }

    out[ENC_OFF + (size_t)(n0 + 0) * NBOOKS + k] = (float)bi.x;
    out[ENC_OFF + (size_t)(n0 + 1) * NBOOKS + k] = (float)bi.y;
    out[ENC_OFF + (size_t)(n0 + 2) * NBOOKS + k] = (float)bi.z;
    out[ENC_OFF + (size_t)(n0 + 3) * NBOOKS + k] = (float)bi.w;
    atomicAdd(&counts[(k << 10) + bi.x], 1);
    atomicAdd(&counts[(k << 10) + bi.y], 1);
    atomicAdd(&counts[(k << 10) + bi.z], 1);
    atomicAdd(&counts[(k << 10) + bi.w], 1);

    for (int off = 32; off; off >>= 1) sq += __shfl_down(sq, off, 64);
    __shared__ float red[4];
    if ((tid & 63) == 0) red[tid >> 6] = sq;
    __syncthreads();
    if (tid == 0)
        partial[blockIdx.y * gridDim.x + blockIdx.x] = (red[0] + red[1]) + (red[2] + red[3]);
}

// ---------------------------------------------------------------- finalize v2
__global__ void __launch_bounds__(256) k_fin(
        const int* __restrict__ counts, const float* __restrict__ partial,
        float* __restrict__ out) {
    __shared__ float shl[4];
    __shared__ float shp[4];
    int tid = threadIdx.x;
    int wave = tid >> 6, lane = tid & 63;

    // loss: 128 partials (32 blocks x 4 books)
    float s = tid < 128 ? partial[tid] : 0.f;
    for (int off = 32; off; off >>= 1) s += __shfl_down(s, off, 64);
    if (lane == 0) shl[wave] = s;

    // perplexity: wave w handles book w, lane handles 16 codes
    float h = 0.f;
    const int* ck = counts + (wave << 10) + lane * 16;
#pragma unroll
    for (int j = 0; j < 16; ++j) {
        float p = (float)ck[j] * (1.f / 32768.f);
        h += p * logf(p + 1e-10f);
    }
    for (int off = 32; off; off >>= 1) h += __shfl_down(h, off, 64);
    if (lane == 0) shp[wave] = expf(-h);
    __syncthreads();
    if (tid == 0) {
        out[LOSS_OFF] = 0.25f * ((shl[0] + shl[1]) + (shl[2] + shl[3])) / 8388608.f;
        out[PERP_OFF] = 0.25f * ((shp[0] + shp[1]) + (shp[2] + shp[3]));
    }
}

// ----------------------------------------------------------------
extern "C" void kernel_launch(void* const* d_in, const int* in_sizes, int n_in,
                              void* d_out, int out_size, void* d_ws, size_t ws_size,
                              hipStream_t stream) {
    const float* z   = (const float*)d_in[0];
    const float* emb = (const float*)d_in[1];
    float* out = (float*)d_out;
    char* ws = (char*)d_ws;

    float*    e2       = (float*)(ws + WS_E2);
    _Float16* ehi      = (_Float16*)(ws + WS_EHI);
    _Float16* elo      = (_Float16*)(ws + WS_ELO);
    int*      idxbuf   = (int*)(ws + WS_IDX);
    int*      counts   = (int*)(ws + WS_CNT);
    float*    partial  = (float*)(ws + WS_PART);
    int*      flagcnt  = (int*)(ws + WS_FLAGCNT);
    int*      flaglist = (int*)(ws + WS_FLAGS);

    k_eprep2<<<16, 256, 0, stream>>>(emb, e2, ehi, elo, counts, flagcnt);

    dim3 agrid(NPOS / 128, NBOOKS);
    k_argmin_mfma<<<agrid, 256, 0, stream>>>(z, e2, ehi, elo, idxbuf, flagcnt, flaglist);
    k_rescore<<<1024, 256, 0, stream>>>(z, emb, e2, flagcnt, flaglist, idxbuf);

    dim3 qgrid(NPOS / 1024, NBOOKS);
    k_quant<<<qgrid, 256, 0, stream>>>(z, emb, idxbuf, out, counts, partial);
    k_fin<<<1, 256, 0, stream>>>(counts, partial, out);
}